// Round 4
// baseline (271.844 us; speedup 1.0000x reference)
//
#include <hip/hip_runtime.h>

// LSTM (B=8192, T=512, H=5) + MLP 5->32->32->5, fp32.
// Round 4: 20 lanes per row -- lane owns ONE (gate,unit) pair and computes a
// single 10-FMA gate dot + one unified sigmoid-form activation
// (tanh(z)=2*sigmoid(2z)-1 via per-lane constants, no divergence).
// 3 rows/wave -> 2731 one-wave blocks = ~2.67 waves/SIMD, so dependency
// stalls of one wave are filled by the others (R1/R3 at 1 wave/SIMD paid
// ~8 cyc/inst on a serial chain; wall tracked inst count with slope 8).
// Cross-lane: ds_bpermute with PREcomputed byte-address registers (1 inst
// per shuffle): 4 gate gathers + 5-wide h broadcast per step.
// Per-step wave stream ~32 insts vs 98 (R3) / 74 (R1).

#define LOG2E 1.44269504088896f

constexpr int TT  = 512;
constexpr int HD  = 5;
constexpr int RPB = 3;      // rows per wave (20 lanes each; lanes 60-63 spare)

__device__ __forceinline__ float hexp2(float x) { return __builtin_amdgcn_exp2f(x); }
__device__ __forceinline__ float hrcp(float x)  { return __builtin_amdgcn_rcpf(x); }

__device__ __forceinline__ float bperm(int byteaddr, float v) {
  return __builtin_bit_cast(float,
      __builtin_amdgcn_ds_bpermute(byteaddr, __builtin_bit_cast(int, v)));
}

// component extract with compile-time-foldable index (post-unroll)
__device__ __forceinline__ float sget(const float4* b, int i) {
  float4 v = b[i >> 2];
  switch (i & 3) { case 0: return v.x; case 1: return v.y;
                   case 2: return v.z; default: return v.w; }
}

__global__ __launch_bounds__(64, 3) void lstm_mlp_kernel(
    const float* __restrict__ x,   const float* __restrict__ Wih,
    const float* __restrict__ Whh, const float* __restrict__ bih,
    const float* __restrict__ bhh, const float* __restrict__ W1,
    const float* __restrict__ b1,  const float* __restrict__ W2,
    const float* __restrict__ b2,  const float* __restrict__ W3,
    const float* __restrict__ b3,  float* __restrict__ out, int B)
{
  const int lane = threadIdx.x;
  const int grp  = lane / 20;          // 0..2 active rows, 3 = spare lanes
  const int u    = lane - grp * 20;    // gate-unit id 0..19
  const int gate = u / 5;              // 0=i 1=f 2=g 3=o (spare lanes: 0..)
  const int j    = u - gate * 5;       // hidden unit 0..4
  const int row  = blockIdx.x * RPB + grp;
  const bool act = (grp < RPB) && (row < B);

  __shared__ float s1[RPB + 1][36];
  __shared__ float s2[RPB + 1][36];

  // ---- per-lane weights: row (gate*5+j) of W_ih / W_hh (valid all lanes) --
  const int wr = gate * 5 + j;         // 0..19
  float wih[5], whh[5];
#pragma unroll
  for (int k = 0; k < 5; ++k) {
    wih[k] = Wih[wr * 5 + k];
    whh[k] = Whh[wr * 5 + k];
  }
  const float bsum = bih[wr] + bhh[wr];

  // activation constants: sigmoid for i/f/o, tanh = 2*sigmoid(2z)-1 for g
  const float cm  = (gate == 2) ? (-2.0f * LOG2E) : (-LOG2E);
  const float Ag  = (gate == 2) ? 2.0f : 1.0f;
  const float Og  = (gate == 2) ? -1.0f : 0.0f;

  // ---- precomputed bpermute byte addresses ----
  const int gbase = grp * 20;
  int ga[4], ba[5];
#pragma unroll
  for (int t = 0; t < 4; ++t) ga[t] = (gbase + t * 5 + j) * 4;  // i,f,g,o of unit j
#pragma unroll
  for (int k = 0; k < 5; ++k) ba[k] = (gbase + k) * 4;          // h_0..h_4

  const float* xrow = x + (size_t)((row < B) ? row : 0) * (TT * HD);

  float c = 0.0f;
  float hv[5] = {0.f, 0.f, 0.f, 0.f, 0.f};

  float4 xa[10], xb[10];
  {
    const float4* p = (const float4*)(xrow);
#pragma unroll
    for (int i = 0; i < 10; ++i) xa[i] = p[i];
  }
  auto load_slab = [&](float4* dst, int t0) {
    const float4* p = (const float4*)(xrow + t0 * HD);
#pragma unroll
    for (int i = 0; i < 10; ++i) dst[i] = p[i];
  };

  auto step = [&](const float4* xs, int s) {
    // x-part (independent of recurrence -> schedulable early)
    float zx = bsum;
#pragma unroll
    for (int k = 0; k < 5; ++k) zx = fmaf(sget(xs, s * 5 + k), wih[k], zx);
    // h-part
    float z = zx;
#pragma unroll
    for (int k = 0; k < 5; ++k) z = fmaf(hv[k], whh[k], z);
    // unified activation
    float a = fmaf(Ag, hrcp(1.0f + hexp2(z * cm)), Og);
    // gather the 4 gate values for unit j
    float qi = bperm(ga[0], a);
    float qf = bperm(ga[1], a);
    float qg = bperm(ga[2], a);
    float qo = bperm(ga[3], a);
    // cell + hidden (computed redundantly on all 20 lanes)
    c = fmaf(qf, c, qi * qg);
    float th = fmaf(2.0f, hrcp(1.0f + hexp2(c * (-2.0f * LOG2E))), -1.0f);
    float h  = qo * th;
    // broadcast h_0..h_4 to every lane of the group
#pragma unroll
    for (int k = 0; k < 5; ++k) hv[k] = bperm(ba[k], h);
  };

#pragma unroll 1
  for (int tc = 0; tc < TT; tc += 16) {
    load_slab(xb, tc + 8);               // tc+8 <= 504, always valid
#pragma unroll
    for (int s = 0; s < 8; ++s) step(xa, s);
    if (tc + 16 < TT) load_slab(xa, tc + 16);
#pragma unroll
    for (int s = 0; s < 8; ++s) step(xb, s);
  }
  // xb floats 35..39 = x[t=511]; hv = h_T (from final broadcast).

  // ---- MLP head (same-wave LDS, no barrier needed; spare lanes use [3]) --
  float in5[5];
#pragma unroll
  for (int k = 0; k < 5; ++k) in5[k] = hv[k] + sget(xb, 35 + k);

  // layer1: lane u computes m=u (0..19) and, for u<16, m=u+16 (16..31;
  // overlap rows 16..19 get identical values from two lanes -- benign).
  {
    float acc = b1[u];
#pragma unroll
    for (int k = 0; k < 5; ++k) acc = fmaf(W1[u * 5 + k], in5[k], acc);
    s1[grp][u] = fmaxf(acc, 0.0f);
    if (u < 16) {
      int m = u + 16;
      float a2 = b1[m];
#pragma unroll
      for (int k = 0; k < 5; ++k) a2 = fmaf(W1[m * 5 + k], in5[k], a2);
      s1[grp][m] = fmaxf(a2, 0.0f);
    }
  }
  float y1[32];
#pragma unroll
  for (int k = 0; k < 32; ++k) y1[k] = s1[grp][k];

  // layer2
  auto dot32 = [&](const float* W, int m, const float* y, float b) {
    float acc = b;
    const float4* w4 = (const float4*)(W + m * 32);
#pragma unroll
    for (int k4 = 0; k4 < 8; ++k4) {
      float4 w = w4[k4];
      acc = fmaf(w.x, y[k4 * 4 + 0], acc);
      acc = fmaf(w.y, y[k4 * 4 + 1], acc);
      acc = fmaf(w.z, y[k4 * 4 + 2], acc);
      acc = fmaf(w.w, y[k4 * 4 + 3], acc);
    }
    return acc;
  };
  s2[grp][u] = fmaxf(dot32(W2, u, y1, b2[u]), 0.0f);
  if (u < 16) {
    int m = u + 16;
    s2[grp][m] = fmaxf(dot32(W2, m, y1, b2[m]), 0.0f);
  }
  float y2[32];
#pragma unroll
  for (int k = 0; k < 32; ++k) y2[k] = s2[grp][k];

  // layer3: lanes u<5 (gate==0, j==u) write out[row*5+u]
  if (act && u < 5) {
    out[row * 5 + u] = dot32(W3, u, y2, b3[u]);
  }
}

extern "C" void kernel_launch(void* const* d_in, const int* in_sizes, int n_in,
                              void* d_out, int out_size, void* d_ws, size_t ws_size,
                              hipStream_t stream) {
  const float* x   = (const float*)d_in[0];
  const float* Wih = (const float*)d_in[1];
  const float* Whh = (const float*)d_in[2];
  const float* bih = (const float*)d_in[3];
  const float* bhh = (const float*)d_in[4];
  const float* W1  = (const float*)d_in[5];
  const float* b1  = (const float*)d_in[6];
  const float* W2  = (const float*)d_in[7];
  const float* b2  = (const float*)d_in[8];
  const float* W3  = (const float*)d_in[9];
  const float* b3  = (const float*)d_in[10];

  int B = in_sizes[0] / (TT * HD);
  int grid = (B + RPB - 1) / RPB;
  hipLaunchKernelGGL(lstm_mlp_kernel, dim3(grid), dim3(64), 0, stream,
                     x, Wih, Whh, bih, bhh, W1, b1, W2, b2, W3, b3,
                     (float*)d_out, B);
}

// Round 6
// 224.999 us; speedup vs baseline: 1.2082x; 1.2082x over previous
//
#include <hip/hip_runtime.h>

// LSTM (B=8192, T=512, H=5) + MLP 5->32->32->5, fp32.
// Round 6 = Round-5 design, compile-fixed (R5 died on an unbalanced macro).
// Geometry: 5 lanes/row, 12 rows/wave, 683 one-wave blocks.
//  - Only 5 ds_bpermute per wave-step -> per-CU DS load ~107 cyc/step
//    (R4's 96 DS-insts/CU/step was its 835-cyc wall).
//  - x double-buffer: named float4 registers, consumed via BY-VALUE lambda
//    args (no arrays / pointer-taking -> SROA keeps them in VGPRs; R3's
//    float4* lambda arg forced scratch and ~8cyc/inst).
//  - __launch_bounds__(64,1): full VGPR budget (~150 live needed).

#define LOG2E 1.44269504088896f

__device__ __forceinline__ float hexp2(float x) { return __builtin_amdgcn_exp2f(x); }
__device__ __forceinline__ float hrcp(float x)  { return __builtin_amdgcn_rcpf(x); }
__device__ __forceinline__ float bp(int addr, float v) {
  return __builtin_bit_cast(float,
      __builtin_amdgcn_ds_bpermute(addr, __builtin_bit_cast(int, v)));
}
// exp2->Inf->rcp->0 saturates correctly; inputs finite -> no clamps needed
__device__ __forceinline__ float fsig(float z) {
  return hrcp(1.0f + hexp2(z * (-LOG2E)));
}
__device__ __forceinline__ float ftanh(float z) {
  return fmaf(-2.0f, hrcp(1.0f + hexp2(z * (2.0f * LOG2E))), 1.0f);
}

constexpr int TT  = 512;
constexpr int HD  = 5;
constexpr int RPB = 12;   // rows per wave (12 groups x 5 lanes; lanes 60-63 spare)

__global__ __launch_bounds__(64, 1) void lstm_mlp_kernel(
    const float* __restrict__ x,   const float* __restrict__ Wih,
    const float* __restrict__ Whh, const float* __restrict__ bih,
    const float* __restrict__ bhh, const float* __restrict__ W1,
    const float* __restrict__ b1,  const float* __restrict__ W2,
    const float* __restrict__ b2,  const float* __restrict__ W3,
    const float* __restrict__ b3,  float* __restrict__ out, int B)
{
  const int lane = threadIdx.x;
  const int g    = lane / 5;            // group 0..11 (12 = spare lanes 60-63)
  const int j    = lane - g * 5;        // hidden unit owned
  const int gg   = (g < RPB) ? g : (RPB - 1);
  const int row  = blockIdx.x * RPB + g;
  const bool act = (g < RPB) && (row < B);

  __shared__ float s1[RPB][36];
  __shared__ float s2[RPB][36];

  // per-lane weights: rows {j,5+j,10+j,15+j} of W_ih/W_hh (i,f,g,o)
  float wih[4][5], whh[4][5], bsum[4];
#pragma unroll
  for (int G = 0; G < 4; ++G) {
#pragma unroll
    for (int k = 0; k < 5; ++k) {
      wih[G][k] = Wih[(G * 5 + j) * 5 + k];
      whh[G][k] = Whh[(G * 5 + j) * 5 + k];
    }
    bsum[G] = bih[G * 5 + j] + bhh[G * 5 + j];
  }

  // bpermute byte addresses for h_0..h_4 of this lane's group
  const int ba0 = (gg * 5 + 0) * 4, ba1 = (gg * 5 + 1) * 4,
            ba2 = (gg * 5 + 2) * 4, ba3 = (gg * 5 + 3) * 4,
            ba4 = (gg * 5 + 4) * 4;

  const int rowc = (row < B) ? row : (B - 1);
  const float* xrow = x + (size_t)rowc * (TT * HD);

  float c = 0.0f;
  float hv0 = 0.0f, hv1 = 0.0f, hv2 = 0.0f, hv3 = 0.0f, hv4 = 0.0f;

  // one LSTM step; x values arrive as BY-VALUE scalars
  auto step = [&](float x0, float x1, float x2, float x3, float x4) {
    float z[4];
#pragma unroll
    for (int G = 0; G < 4; ++G) {
      float a = bsum[G];
      a = fmaf(x0, wih[G][0], a);
      a = fmaf(x1, wih[G][1], a);
      a = fmaf(x2, wih[G][2], a);
      a = fmaf(x3, wih[G][3], a);
      a = fmaf(x4, wih[G][4], a);
      a = fmaf(hv0, whh[G][0], a);
      a = fmaf(hv1, whh[G][1], a);
      a = fmaf(hv2, whh[G][2], a);
      a = fmaf(hv3, whh[G][3], a);
      a = fmaf(hv4, whh[G][4], a);
      z[G] = a;
    }
    float ig = fsig(z[0]);
    float fg = fsig(z[1]);
    float gv = ftanh(z[2]);
    float og = fsig(z[3]);
    c = fmaf(fg, c, ig * gv);
    float h = og * ftanh(c);
    hv0 = bp(ba0, h); hv1 = bp(ba1, h); hv2 = bp(ba2, h);
    hv3 = bp(ba3, h); hv4 = bp(ba4, h);
  };

  // 8 steps over one slab (10 float4 = 40 floats), all by value
  auto step8 = [&](float4 s0, float4 s1, float4 s2, float4 s3, float4 s4,
                   float4 s5, float4 s6, float4 s7, float4 s8, float4 s9) {
    step(s0.x, s0.y, s0.z, s0.w, s1.x);
    step(s1.y, s1.z, s1.w, s2.x, s2.y);
    step(s2.z, s2.w, s3.x, s3.y, s3.z);
    step(s3.w, s4.x, s4.y, s4.z, s4.w);
    step(s5.x, s5.y, s5.z, s5.w, s6.x);
    step(s6.y, s6.z, s6.w, s7.x, s7.y);
    step(s7.z, s7.w, s8.x, s8.y, s8.z);
    step(s8.w, s9.x, s9.y, s9.z, s9.w);
  };

  // double-buffered x slabs: named registers only
  float4 a0, a1, a2, a3, a4, a5, a6, a7, a8, a9;
  float4 c0, c1, c2, c3, c4, c5, c6, c7, c8, c9;

  {
    const float4* p = (const float4*)(xrow);
    a0 = p[0]; a1 = p[1]; a2 = p[2]; a3 = p[3]; a4 = p[4];
    a5 = p[5]; a6 = p[6]; a7 = p[7]; a8 = p[8]; a9 = p[9];
  }

#pragma unroll 1
  for (int tc = 0; tc < TT; tc += 16) {
    {
      const float4* p = (const float4*)(xrow + (tc + 8) * HD);
      c0 = p[0]; c1 = p[1]; c2 = p[2]; c3 = p[3]; c4 = p[4];
      c5 = p[5]; c6 = p[6]; c7 = p[7]; c8 = p[8]; c9 = p[9];
    }
    step8(a0, a1, a2, a3, a4, a5, a6, a7, a8, a9);
    if (tc + 16 < TT) {
      const float4* p = (const float4*)(xrow + (tc + 16) * HD);
      a0 = p[0]; a1 = p[1]; a2 = p[2]; a3 = p[3]; a4 = p[4];
      a5 = p[5]; a6 = p[6]; a7 = p[7]; a8 = p[8]; a9 = p[9];
    }
    step8(c0, c1, c2, c3, c4, c5, c6, c7, c8, c9);
  }
  // c-slab holds t=504..511: x[t=511] = floats 35..39 = c8.w, c9.xyzw

  // ---- MLP head (single wave; LDS writes masked to active lanes) ----
  float in5_0 = hv0 + c8.w;
  float in5_1 = hv1 + c9.x;
  float in5_2 = hv2 + c9.y;
  float in5_3 = hv3 + c9.z;
  float in5_4 = hv4 + c9.w;

  // layer1: lane j covers m = j + 5p (m < 32)
#pragma unroll
  for (int p = 0; p < 7; ++p) {
    int m = j + 5 * p;
    if (m < 32) {
      float acc = b1[m];
      acc = fmaf(W1[m * 5 + 0], in5_0, acc);
      acc = fmaf(W1[m * 5 + 1], in5_1, acc);
      acc = fmaf(W1[m * 5 + 2], in5_2, acc);
      acc = fmaf(W1[m * 5 + 3], in5_3, acc);
      acc = fmaf(W1[m * 5 + 4], in5_4, acc);
      if (act) s1[gg][m] = fmaxf(acc, 0.0f);
    }
  }
  float y1[32];
#pragma unroll
  for (int k = 0; k < 32; ++k) y1[k] = s1[gg][k];

  // layer2
#pragma unroll
  for (int p = 0; p < 7; ++p) {
    int m = j + 5 * p;
    if (m < 32) {
      float acc = b2[m];
      const float4* w4 = (const float4*)(W2 + m * 32);
#pragma unroll
      for (int k4 = 0; k4 < 8; ++k4) {
        float4 w = w4[k4];
        acc = fmaf(w.x, y1[k4 * 4 + 0], acc);
        acc = fmaf(w.y, y1[k4 * 4 + 1], acc);
        acc = fmaf(w.z, y1[k4 * 4 + 2], acc);
        acc = fmaf(w.w, y1[k4 * 4 + 3], acc);
      }
      if (act) s2[gg][m] = fmaxf(acc, 0.0f);
    }
  }
  float y2[32];
#pragma unroll
  for (int k = 0; k < 32; ++k) y2[k] = s2[gg][k];

  // layer3: each active lane writes out[row*5 + j]
  if (act) {
    float acc = b3[j];
    const float4* w4 = (const float4*)(W3 + j * 32);
#pragma unroll
    for (int k4 = 0; k4 < 8; ++k4) {
      float4 w = w4[k4];
      acc = fmaf(w.x, y2[k4 * 4 + 0], acc);
      acc = fmaf(w.y, y2[k4 * 4 + 1], acc);
      acc = fmaf(w.z, y2[k4 * 4 + 2], acc);
      acc = fmaf(w.w, y2[k4 * 4 + 3], acc);
    }
    out[row * 5 + j] = acc;
  }
}

extern "C" void kernel_launch(void* const* d_in, const int* in_sizes, int n_in,
                              void* d_out, int out_size, void* d_ws, size_t ws_size,
                              hipStream_t stream) {
  const float* x   = (const float*)d_in[0];
  const float* Wih = (const float*)d_in[1];
  const float* Whh = (const float*)d_in[2];
  const float* bih = (const float*)d_in[3];
  const float* bhh = (const float*)d_in[4];
  const float* W1  = (const float*)d_in[5];
  const float* b1  = (const float*)d_in[6];
  const float* W2  = (const float*)d_in[7];
  const float* b2  = (const float*)d_in[8];
  const float* W3  = (const float*)d_in[9];
  const float* b3  = (const float*)d_in[10];

  int B = in_sizes[0] / (TT * HD);
  int grid = (B + RPB - 1) / RPB;
  hipLaunchKernelGGL(lstm_mlp_kernel, dim3(grid), dim3(64), 0, stream,
                     x, Wih, Whh, bih, bhh, W1, b1, W2, b2, W3, b3,
                     (float*)d_out, B);
}

// Round 7
// 220.337 us; speedup vs baseline: 1.2338x; 1.0212x over previous
//
#include <hip/hip_runtime.h>

// LSTM (B=8192, T=512, H=5) + MLP 5->32->32->5, fp32.
// Round 7 = Round-6 + anti-sink register pins.
// R1/R6 both ended at VGPR=76 / ~575 cyc/step: the compiler SINKS the slab
// loads into the step bodies (legal: loads are pure), putting global latency
// on the serial recurrence chain. Empty `asm volatile("" : "+v"(x))` pins
// make the loaded values opaque at the pin site -- the load cannot be sunk
// past it or rematerialized. Pins are placed a half-iteration after the
// load's issue (A pinned after C's prefetch is issued), so the vmcnt wait
// lands ~1200 cyc after issue and HBM latency is fully hidden.
// Also: activation scale factors folded into per-lane weights (saves 4
// v_mul/step): gates i,f,o scaled by -log2e (sig = rcp(1+exp2(z'))),
// gate g scaled by 2*log2e (tanh = 1 - 2*rcp(1+exp2(z'))).

#define LOG2E 1.44269504088896f

__device__ __forceinline__ float hexp2(float x) { return __builtin_amdgcn_exp2f(x); }
__device__ __forceinline__ float hrcp(float x)  { return __builtin_amdgcn_rcpf(x); }
__device__ __forceinline__ float bp(int addr, float v) {
  return __builtin_bit_cast(float,
      __builtin_amdgcn_ds_bpermute(addr, __builtin_bit_cast(int, v)));
}
__device__ __forceinline__ void pin4(float4& v) {
  asm volatile("" : "+v"(v.x), "+v"(v.y), "+v"(v.z), "+v"(v.w));
}

constexpr int TT  = 512;
constexpr int HD  = 5;
constexpr int RPB = 12;   // rows per wave (12 groups x 5 lanes; lanes 60-63 spare)

__global__ __launch_bounds__(64, 1) void lstm_mlp_kernel(
    const float* __restrict__ x,   const float* __restrict__ Wih,
    const float* __restrict__ Whh, const float* __restrict__ bih,
    const float* __restrict__ bhh, const float* __restrict__ W1,
    const float* __restrict__ b1,  const float* __restrict__ W2,
    const float* __restrict__ b2,  const float* __restrict__ W3,
    const float* __restrict__ b3,  float* __restrict__ out, int B)
{
  const int lane = threadIdx.x;
  const int g    = lane / 5;            // group 0..11 (12 = spare lanes 60-63)
  const int j    = lane - g * 5;        // hidden unit owned
  const int gg   = (g < RPB) ? g : (RPB - 1);
  const int row  = blockIdx.x * RPB + g;
  const bool act = (g < RPB) && (row < B);

  __shared__ float s1[RPB][36];
  __shared__ float s2[RPB][36];

  // per-lane weights: rows {j,5+j,10+j,15+j} of W_ih/W_hh (i,f,g,o),
  // pre-scaled by the activation argument factor.
  float wih[4][5], whh[4][5], bsum[4];
#pragma unroll
  for (int G = 0; G < 4; ++G) {
    const float sc = (G == 2) ? (2.0f * LOG2E) : (-LOG2E);
#pragma unroll
    for (int k = 0; k < 5; ++k) {
      wih[G][k] = Wih[(G * 5 + j) * 5 + k] * sc;
      whh[G][k] = Whh[(G * 5 + j) * 5 + k] * sc;
    }
    bsum[G] = (bih[G * 5 + j] + bhh[G * 5 + j]) * sc;
  }

  // bpermute byte addresses for h_0..h_4 of this lane's group
  const int ba0 = (gg * 5 + 0) * 4, ba1 = (gg * 5 + 1) * 4,
            ba2 = (gg * 5 + 2) * 4, ba3 = (gg * 5 + 3) * 4,
            ba4 = (gg * 5 + 4) * 4;

  const int rowc = (row < B) ? row : (B - 1);
  const float* xrow = x + (size_t)rowc * (TT * HD);

  float c = 0.0f;
  float hv0 = 0.0f, hv1 = 0.0f, hv2 = 0.0f, hv3 = 0.0f, hv4 = 0.0f;

  // one LSTM step; x values arrive as BY-VALUE scalars.
  // z' already includes the activation scale: i,f,o: sig=rcp(1+exp2(z'));
  // g: tanh=1-2*rcp(1+exp2(z')).
  auto step = [&](float x0, float x1, float x2, float x3, float x4) {
    float z[4];
#pragma unroll
    for (int G = 0; G < 4; ++G) {
      float a = bsum[G];
      a = fmaf(x0, wih[G][0], a);
      a = fmaf(x1, wih[G][1], a);
      a = fmaf(x2, wih[G][2], a);
      a = fmaf(x3, wih[G][3], a);
      a = fmaf(x4, wih[G][4], a);
      a = fmaf(hv0, whh[G][0], a);
      a = fmaf(hv1, whh[G][1], a);
      a = fmaf(hv2, whh[G][2], a);
      a = fmaf(hv3, whh[G][3], a);
      a = fmaf(hv4, whh[G][4], a);
      z[G] = a;
    }
    float ig = hrcp(1.0f + hexp2(z[0]));
    float fg = hrcp(1.0f + hexp2(z[1]));
    float gv = fmaf(-2.0f, hrcp(1.0f + hexp2(z[2])), 1.0f);
    float og = hrcp(1.0f + hexp2(z[3]));
    c = fmaf(fg, c, ig * gv);
    float th = fmaf(-2.0f, hrcp(1.0f + hexp2(c * (2.0f * LOG2E))), 1.0f);
    float h = og * th;
    hv0 = bp(ba0, h); hv1 = bp(ba1, h); hv2 = bp(ba2, h);
    hv3 = bp(ba3, h); hv4 = bp(ba4, h);
  };

  // 8 steps over one slab (10 float4 = 40 floats), all by value
  auto step8 = [&](float4 s0, float4 s1, float4 s2, float4 s3, float4 s4,
                   float4 s5, float4 s6, float4 s7, float4 s8, float4 s9) {
    step(s0.x, s0.y, s0.z, s0.w, s1.x);
    step(s1.y, s1.z, s1.w, s2.x, s2.y);
    step(s2.z, s2.w, s3.x, s3.y, s3.z);
    step(s3.w, s4.x, s4.y, s4.z, s4.w);
    step(s5.x, s5.y, s5.z, s5.w, s6.x);
    step(s6.y, s6.z, s6.w, s7.x, s7.y);
    step(s7.z, s7.w, s8.x, s8.y, s8.z);
    step(s8.w, s9.x, s9.y, s9.z, s9.w);
  };

  // double-buffered x slabs: named registers, pinned against load sinking
  float4 a0, a1, a2, a3, a4, a5, a6, a7, a8, a9;
  float4 c0, c1, c2, c3, c4, c5, c6, c7, c8, c9;

  {
    const float4* p = (const float4*)(xrow);
    a0 = p[0]; a1 = p[1]; a2 = p[2]; a3 = p[3]; a4 = p[4];
    a5 = p[5]; a6 = p[6]; a7 = p[7]; a8 = p[8]; a9 = p[9];
  }

#pragma unroll 1
  for (int tc = 0; tc < TT; tc += 16) {
    {
      const float4* p = (const float4*)(xrow + (tc + 8) * HD);
      c0 = p[0]; c1 = p[1]; c2 = p[2]; c3 = p[3]; c4 = p[4];
      c5 = p[5]; c6 = p[6]; c7 = p[7]; c8 = p[8]; c9 = p[9];
    }
    // pin A: its loads were issued a half-iteration ago -> wait is free.
    pin4(a0); pin4(a1); pin4(a2); pin4(a3); pin4(a4);
    pin4(a5); pin4(a6); pin4(a7); pin4(a8); pin4(a9);
    step8(a0, a1, a2, a3, a4, a5, a6, a7, a8, a9);
    if (tc + 16 < TT) {
      const float4* p = (const float4*)(xrow + (tc + 16) * HD);
      a0 = p[0]; a1 = p[1]; a2 = p[2]; a3 = p[3]; a4 = p[4];
      a5 = p[5]; a6 = p[6]; a7 = p[7]; a8 = p[8]; a9 = p[9];
    }
    // pin C: issued at loop top, ~8 steps of compute have passed.
    pin4(c0); pin4(c1); pin4(c2); pin4(c3); pin4(c4);
    pin4(c5); pin4(c6); pin4(c7); pin4(c8); pin4(c9);
    step8(c0, c1, c2, c3, c4, c5, c6, c7, c8, c9);
  }
  // c-slab holds t=504..511: x[t=511] = floats 35..39 = c8.w, c9.xyzw

  // ---- MLP head (single wave; LDS writes masked to active lanes) ----
  float in5_0 = hv0 + c8.w;
  float in5_1 = hv1 + c9.x;
  float in5_2 = hv2 + c9.y;
  float in5_3 = hv3 + c9.z;
  float in5_4 = hv4 + c9.w;

  // layer1: lane j covers m = j + 5p (m < 32)
#pragma unroll
  for (int p = 0; p < 7; ++p) {
    int m = j + 5 * p;
    if (m < 32) {
      float acc = b1[m];
      acc = fmaf(W1[m * 5 + 0], in5_0, acc);
      acc = fmaf(W1[m * 5 + 1], in5_1, acc);
      acc = fmaf(W1[m * 5 + 2], in5_2, acc);
      acc = fmaf(W1[m * 5 + 3], in5_3, acc);
      acc = fmaf(W1[m * 5 + 4], in5_4, acc);
      if (act) s1[gg][m] = fmaxf(acc, 0.0f);
    }
  }
  float y1[32];
#pragma unroll
  for (int k = 0; k < 32; ++k) y1[k] = s1[gg][k];

  // layer2
#pragma unroll
  for (int p = 0; p < 7; ++p) {
    int m = j + 5 * p;
    if (m < 32) {
      float acc = b2[m];
      const float4* w4 = (const float4*)(W2 + m * 32);
#pragma unroll
      for (int k4 = 0; k4 < 8; ++k4) {
        float4 w = w4[k4];
        acc = fmaf(w.x, y1[k4 * 4 + 0], acc);
        acc = fmaf(w.y, y1[k4 * 4 + 1], acc);
        acc = fmaf(w.z, y1[k4 * 4 + 2], acc);
        acc = fmaf(w.w, y1[k4 * 4 + 3], acc);
      }
      if (act) s2[gg][m] = fmaxf(acc, 0.0f);
    }
  }
  float y2[32];
#pragma unroll
  for (int k = 0; k < 32; ++k) y2[k] = s2[gg][k];

  // layer3: each active lane writes out[row*5 + j]
  if (act) {
    float acc = b3[j];
    const float4* w4 = (const float4*)(W3 + j * 32);
#pragma unroll
    for (int k4 = 0; k4 < 8; ++k4) {
      float4 w = w4[k4];
      acc = fmaf(w.x, y2[k4 * 4 + 0], acc);
      acc = fmaf(w.y, y2[k4 * 4 + 1], acc);
      acc = fmaf(w.z, y2[k4 * 4 + 2], acc);
      acc = fmaf(w.w, y2[k4 * 4 + 3], acc);
    }
    out[row * 5 + j] = acc;
  }
}

extern "C" void kernel_launch(void* const* d_in, const int* in_sizes, int n_in,
                              void* d_out, int out_size, void* d_ws, size_t ws_size,
                              hipStream_t stream) {
  const float* x   = (const float*)d_in[0];
  const float* Wih = (const float*)d_in[1];
  const float* Whh = (const float*)d_in[2];
  const float* bih = (const float*)d_in[3];
  const float* bhh = (const float*)d_in[4];
  const float* W1  = (const float*)d_in[5];
  const float* b1  = (const float*)d_in[6];
  const float* W2  = (const float*)d_in[7];
  const float* b2  = (const float*)d_in[8];
  const float* W3  = (const float*)d_in[9];
  const float* b3  = (const float*)d_in[10];

  int B = in_sizes[0] / (TT * HD);
  int grid = (B + RPB - 1) / RPB;
  hipLaunchKernelGGL(lstm_mlp_kernel, dim3(grid), dim3(64), 0, stream,
                     x, Wih, Whh, bih, bhh, W1, b1, W2, b2, W3, b3,
                     (float*)d_out, B);
}